// Round 8
// baseline (1458.392 us; speedup 1.0000x reference)
//
#include <hip/hip_runtime.h>
#include <hip/hip_bf16.h>

// Problem: VectorQuantizer. z: [32,256,32,32] f32 NCHW, codebook: [1024,256] f32.
// Outputs (concat f32): z_q_out [32,256,32,32], loss[1], perplexity[1], idx[32768] (as float), mean_distance[1].
// N = 32768 points, K = 1024 codes, D = 256.
// idx must replicate numpy-fp32 argmin of d = fl32(fl32(s_n + t_k) - 2*fl32(dot)).

#define NPTS   32768
#define KCODE  1024
#define DDIM   256
#define HWSZ   1024     // 32*32
#define ZSTRB  262144   // 256*1024 floats per batch
#define ZELEMS 8388608

#define OUT_LOSS 8388608
#define OUT_PERP 8388609
#define OUT_IDX  8388610
#define OUT_MD   8421378

// ws byte offsets (total ~4.5 MB assumed available)
#define WS_IDX     0        // int[32768]
#define WS_COUNTS  131072   // int[1024]
#define WS_RLIST   135168   // int[32768]
#define WS_RCOUNT  266240   // int
#define WS_LOSSSUM 266248   // double
#define WS_ZSQ     266256   // double
#define WS_ENSUM   266264   // double
#define WS_CHSUM   266272   // double[256]
#define WS_ESUM    268320   // double[256]
#define WS_ENORM   270368   // float[1024]  (np-fp32 pairwise ||e_k||^2)
#define WS_CBT     274464   // float[256*1024]  codebook transposed [d][k]
#define WS_COLB    1323040  // float[8][32768] per-column best
#define WS_COLS    2371616  // float[8][32768] per-column second
#define WS_COLI    3420192  // int[8][32768]   per-column argmin

// flip can only happen if exact top-2 gap < 2*ulp(256)+dot_err ~ 6.2e-5; 2x margin
#define MARGIN 1.2e-4f

#define CPB 128   // codes per block-column (8 columns)
#define DC  8     // d-chunk held in registers

__global__ __launch_bounds__(256) void init_kernel(char* ws) {
    int t = threadIdx.x;
    int* counts = (int*)(ws + WS_COUNTS);
    for (int i = t; i < 1024; i += 256) counts[i] = 0;
    if (t == 0) *(int*)(ws + WS_RCOUNT) = 0;
    double* dbl = (double*)(ws + WS_LOSSSUM);
    for (int i = t; i < 515; i += 256) dbl[i] = 0.0;  // losssum,zsq,ensum + chsum[256] + esum[256]
}

// numpy pairwise fp32 sum of squares of a 256-row, exact tree:
// two 128-blocks (8 strided accumulators, ((r0+r1)+(r2+r3))+((r4+r5)+(r6+r7))), then block0+block1.
// asm barriers stop ffp-contract from fusing square into the add.
__device__ __forceinline__ float np_sumsq256(const float* p) {
    float tot[2];
    #pragma unroll
    for (int h = 0; h < 2; ++h) {
        const float* a = p + h * 128;
        float r[8];
        #pragma unroll
        for (int j = 0; j < 8; ++j) { float v = a[j]; float s = v * v; asm volatile("" : "+v"(s)); r[j] = s; }
        for (int i = 8; i < 128; i += 8) {
            #pragma unroll
            for (int j = 0; j < 8; ++j) { float v = a[i + j]; float s = v * v; asm volatile("" : "+v"(s)); r[j] += s; }
        }
        tot[h] = ((r[0] + r[1]) + (r[2] + r[3])) + ((r[4] + r[5]) + (r[6] + r[7]));
    }
    return tot[0] + tot[1];
}

// LDS-tiled: per 64 codes -> np-fp32 enorm, transposed cbT[d][k], fp64 column sums, fp64 norm total.
__global__ __launch_bounds__(256) void prep2_kernel(const float* __restrict__ cb,
                                                    float* __restrict__ enorm,
                                                    float* __restrict__ cbT,
                                                    double* __restrict__ esum,
                                                    double* __restrict__ enormsum) {
    __shared__ float tile[64][257];     // pad breaks bank alignment
    int t = threadIdx.x;
    int k0 = blockIdx.x * 64;           // 16 blocks

    // stage 64 rows, coalesced float4 reads
    for (int i = 0; i < 16; ++i) {
        int f = t + 256 * i;            // float4 index
        int r = f >> 6;                 // code row 0..63
        int c4 = (f & 63) << 2;         // channel 0..252
        float4 v = *(const float4*)(cb + (size_t)(k0 + r) * DDIM + c4);
        tile[r][c4] = v.x; tile[r][c4 + 1] = v.y; tile[r][c4 + 2] = v.z; tile[r][c4 + 3] = v.w;
    }
    __syncthreads();

    // enorm (numpy pairwise fp32) + block norm total
    if (t < 64) {
        float s = np_sumsq256(&tile[t][0]);
        enorm[k0 + t] = s;
        double en = (double)s;
        for (int o = 32; o; o >>= 1) en += __shfl_down(en, o, 64);
        if (t == 0) atomicAdd(enormsum, en);
    }

    // fp64 column sums: thread t owns channel t
    double cs = 0.0;
    for (int r = 0; r < 64; ++r) cs += (double)tile[r][t];
    atomicAdd(&esum[t], cs);

    // transposed write: quarter-wave per d-phase, 64 consecutive k per row
    int kloc = t & 63, dq = t >> 6;
    for (int dd = 0; dd < 64; ++dd) {
        int d = dd * 4 + dq;
        cbT[(size_t)d * KCODE + k0 + kloc] = tile[kloc][d];
    }
}

// Phase 1 screen: thread owns one point and CPB codes. z d-chunk in registers,
// codebook streamed as uniform VMEM loads (vzero keeps them off the scalar pipe).
// Fully-unrolled straight-line bursts let the scheduler hoist loads across bursts.
__global__ __launch_bounds__(256, 2) void screen_kernel(const float* __restrict__ z,
                                                        const float* __restrict__ cb,
                                                        const float* __restrict__ enorm,
                                                        float* __restrict__ colb,
                                                        float* __restrict__ cols,
                                                        int* __restrict__ coli) {
    int t = threadIdx.x;
    int n = blockIdx.x * 256 + t;        // point
    int col = blockIdx.y;                // code column
    int k0 = col * CPB;
    int b = n >> 10, hw = n & 1023;
    const float* zp = z + (size_t)b * ZSTRB + hw;

    // opaque zero in a VGPR: forces codebook loads onto VMEM (vmcnt, in-order)
    int vzero;
    asm("v_mov_b32 %0, 0" : "=v"(vzero));
    const char* cbase = (const char*)(cb + (size_t)k0 * DDIM) + vzero;

    float acc[CPB];
    #pragma unroll
    for (int i = 0; i < CPB; ++i) acc[i] = 0.f;

    #pragma unroll 1
    for (int dc = 0; dc < DDIM; dc += DC) {   // 32 iters, body straight-line
        float zr[DC];
        #pragma unroll
        for (int j = 0; j < DC; ++j) zr[j] = zp[(dc + j) << 10];
        const char* cb2 = cbase + dc * 4;
        #pragma unroll
        for (int cs = 0; cs < CPB; cs += 4) {
            const char* cp = cb2 + (size_t)cs * 1024;
            float4 q00 = *(const float4*)(cp + 0 * 1024);
            float4 q01 = *(const float4*)(cp + 0 * 1024 + 16);
            float4 q10 = *(const float4*)(cp + 1 * 1024);
            float4 q11 = *(const float4*)(cp + 1 * 1024 + 16);
            float4 q20 = *(const float4*)(cp + 2 * 1024);
            float4 q21 = *(const float4*)(cp + 2 * 1024 + 16);
            float4 q30 = *(const float4*)(cp + 3 * 1024);
            float4 q31 = *(const float4*)(cp + 3 * 1024 + 16);
            acc[cs+0] = fmaf(zr[0], q00.x, acc[cs+0]); acc[cs+0] = fmaf(zr[1], q00.y, acc[cs+0]);
            acc[cs+0] = fmaf(zr[2], q00.z, acc[cs+0]); acc[cs+0] = fmaf(zr[3], q00.w, acc[cs+0]);
            acc[cs+0] = fmaf(zr[4], q01.x, acc[cs+0]); acc[cs+0] = fmaf(zr[5], q01.y, acc[cs+0]);
            acc[cs+0] = fmaf(zr[6], q01.z, acc[cs+0]); acc[cs+0] = fmaf(zr[7], q01.w, acc[cs+0]);
            acc[cs+1] = fmaf(zr[0], q10.x, acc[cs+1]); acc[cs+1] = fmaf(zr[1], q10.y, acc[cs+1]);
            acc[cs+1] = fmaf(zr[2], q10.z, acc[cs+1]); acc[cs+1] = fmaf(zr[3], q10.w, acc[cs+1]);
            acc[cs+1] = fmaf(zr[4], q11.x, acc[cs+1]); acc[cs+1] = fmaf(zr[5], q11.y, acc[cs+1]);
            acc[cs+1] = fmaf(zr[6], q11.z, acc[cs+1]); acc[cs+1] = fmaf(zr[7], q11.w, acc[cs+1]);
            acc[cs+2] = fmaf(zr[0], q20.x, acc[cs+2]); acc[cs+2] = fmaf(zr[1], q20.y, acc[cs+2]);
            acc[cs+2] = fmaf(zr[2], q20.z, acc[cs+2]); acc[cs+2] = fmaf(zr[3], q20.w, acc[cs+2]);
            acc[cs+2] = fmaf(zr[4], q21.x, acc[cs+2]); acc[cs+2] = fmaf(zr[5], q21.y, acc[cs+2]);
            acc[cs+2] = fmaf(zr[6], q21.z, acc[cs+2]); acc[cs+2] = fmaf(zr[7], q21.w, acc[cs+2]);
            acc[cs+3] = fmaf(zr[0], q30.x, acc[cs+3]); acc[cs+3] = fmaf(zr[1], q30.y, acc[cs+3]);
            acc[cs+3] = fmaf(zr[2], q30.z, acc[cs+3]); acc[cs+3] = fmaf(zr[3], q30.w, acc[cs+3]);
            acc[cs+3] = fmaf(zr[4], q31.x, acc[cs+3]); acc[cs+3] = fmaf(zr[5], q31.y, acc[cs+3]);
            acc[cs+3] = fmaf(zr[6], q31.z, acc[cs+3]); acc[cs+3] = fmaf(zr[7], q31.w, acc[cs+3]);
        }
    }

    // epilogue: criterion + best/sec/idx over this column's codes (ascending => lowest-index ties)
    float best = 3.4e38f, sec = 3.4e38f;
    int bidx = 0;
    #pragma unroll
    for (int i = 0; i < CPB; ++i) {
        float c = fmaf(-2.f, acc[i], enorm[k0 + i]);
        if (c < best) { sec = best; best = c; bidx = k0 + i; } else if (c < sec) sec = c;
    }
    colb[col * NPTS + n] = best;
    cols[col * NPTS + n] = sec;
    coli[col * NPTS + n] = bidx;
}

// merge 8 columns (ascending code order preserves lowest-index tiebreak) + margin flag
__global__ __launch_bounds__(256) void merge_kernel(const float* __restrict__ colb,
                                                    const float* __restrict__ cols,
                                                    const int* __restrict__ coli,
                                                    int* __restrict__ ws_idx,
                                                    int* __restrict__ rlist,
                                                    int* __restrict__ rcount) {
    int n = blockIdx.x * 256 + threadIdx.x;
    float B = colb[n]; float S = cols[n]; int I = coli[n];
    #pragma unroll
    for (int c2 = 1; c2 < 8; ++c2) {
        float b2 = colb[c2 * NPTS + n], s2 = cols[c2 * NPTS + n];
        if (b2 < B) { S = fminf(B, s2); I = coli[c2 * NPTS + n]; B = b2; }
        else        { S = fminf(S, b2); }
    }
    ws_idx[n] = I;
    if (S - B < MARGIN) {
        int slot = atomicAdd(rcount, 1);
        if (slot < NPTS) rlist[slot] = n;
    }
}

// Recheck flagged points replicating numpy fp32 semantics:
// d(k) = fl32( fl32(s_n + t_k) - 2*fl32(dot64(z,e_k)) ), argmin with first-index tiebreak.
__global__ __launch_bounds__(256) void recheck_kernel(const float* __restrict__ z,
                                                      const float* __restrict__ cbT,
                                                      const float* __restrict__ enorm,
                                                      int* __restrict__ ws_idx,
                                                      const int* __restrict__ rlist,
                                                      const int* __restrict__ rcount) {
    __shared__ float zs[DDIM];
    __shared__ float s_sh;
    __shared__ float bv[256];
    __shared__ int   bi[256];
    int t = threadIdx.x;
    int cnt = *rcount; if (cnt > NPTS) cnt = NPTS;
    for (int it = blockIdx.x; it < cnt; it += gridDim.x) {
        int n = rlist[it];
        int b = n >> 10, hw = n & 1023;
        zs[t] = z[(size_t)b * ZSTRB + (size_t)t * HWSZ + hw];
        __syncthreads();
        if (t == 0) s_sh = np_sumsq256(zs);   // numpy pairwise fp32 ||z_n||^2
        __syncthreads();
        float s_n = s_sh;
        float best = 3.4e38f; int bidx = 0;
        #pragma unroll
        for (int j = 0; j < 4; ++j) {
            int k = t + 256 * j;
            double dot = 0.0;
            for (int d = 0; d < DDIM; ++d)
                dot = fma((double)cbT[d * KCODE + k], (double)zs[d], dot);
            float E = (float)dot;            // einsum's fp32 value (to ~3e-9)
            float w = 2.0f * E;              // exact x2
            float u = s_n + enorm[k];        // fp32 add
            float dd = u - w;                // fp32 sub
            if (dd < best) { best = dd; bidx = k; }   // j ascending => lowest k kept
        }
        bv[t] = best; bi[t] = bidx;
        __syncthreads();
        for (int s2 = 128; s2; s2 >>= 1) {
            if (t < s2) {
                if (bv[t + s2] < bv[t] || (bv[t + s2] == bv[t] && bi[t + s2] < bi[t])) {
                    bv[t] = bv[t + s2]; bi[t] = bi[t + s2];
                }
            }
            __syncthreads();
        }
        if (t == 0) ws_idx[n] = bi[0];
        __syncthreads();
    }
}

// histogram + idx-as-float output (after recheck so counts reflect final idx)
__global__ __launch_bounds__(256) void hist_kernel(const int* __restrict__ ws_idx,
                                                   int* __restrict__ counts,
                                                   float* __restrict__ out_idx) {
    __shared__ int h[KCODE];
    int t = threadIdx.x;
    for (int i = t; i < KCODE; i += 256) h[i] = 0;
    __syncthreads();
    int n = blockIdx.x * 256 + t;
    int idx = ws_idx[n];
    out_idx[n] = (float)idx;
    atomicAdd(&h[idx], 1);
    __syncthreads();
    for (int i = t; i < KCODE; i += 256) { int c = h[i]; if (c) atomicAdd(&counts[i], c); }
}

// z_q_out (straight-through rounding replicated) + loss sum + z channel sums + z^2 total
__global__ __launch_bounds__(256) void out_kernel(const float* __restrict__ z,
                                                  const float* __restrict__ cb,
                                                  const int* __restrict__ ws_idx,
                                                  float* __restrict__ out,
                                                  double* __restrict__ lossSum,
                                                  double* __restrict__ chsum,
                                                  double* __restrict__ zsq) {
    int t = threadIdx.x;
    size_t base = (size_t)blockIdx.x * 1024;
    int c = blockIdx.x & 255;          // channel, constant per block
    int b = blockIdx.x >> 8;
    int hw = t * 4;
    const float4 zv = *(const float4*)(z + base + hw);
    int4 iv = *(const int4*)(ws_idx + b * HWSZ + hw);
    float q0 = cb[(size_t)iv.x * DDIM + c];
    float q1 = cb[(size_t)iv.y * DDIM + c];
    float q2 = cb[(size_t)iv.z * DDIM + c];
    float q3 = cb[(size_t)iv.w * DDIM + c];
    float t0 = q0 - zv.x, t1 = q1 - zv.y, t2 = q2 - zv.z, t3 = q3 - zv.w;
    float4 o; o.x = zv.x + t0; o.y = zv.y + t1; o.z = zv.z + t2; o.w = zv.w + t3;
    *(float4*)(out + base + hw) = o;

    double ls  = (double)t0 * t0 + (double)t1 * t1 + (double)t2 * t2 + (double)t3 * t3;
    double zs  = (double)zv.x + (double)zv.y + (double)zv.z + (double)zv.w;
    double zq2 = (double)zv.x * zv.x + (double)zv.y * zv.y + (double)zv.z * zv.z + (double)zv.w * zv.w;

    __shared__ double r1[4], r2[4], r3[4];
    for (int o2 = 32; o2; o2 >>= 1) {
        ls  += __shfl_down(ls,  o2, 64);
        zs  += __shfl_down(zs,  o2, 64);
        zq2 += __shfl_down(zq2, o2, 64);
    }
    if ((t & 63) == 0) { int w = t >> 6; r1[w] = ls; r2[w] = zs; r3[w] = zq2; }
    __syncthreads();
    if (t == 0) {
        atomicAdd(lossSum, r1[0] + r1[1] + r1[2] + r1[3]);
        atomicAdd(&chsum[c], r2[0] + r2[1] + r2[2] + r2[3]);
        atomicAdd(zsq, r3[0] + r3[1] + r3[2] + r3[3]);
    }
}

__global__ __launch_bounds__(256) void fin_kernel(const int* __restrict__ counts,
                                                  const double* __restrict__ lossSum,
                                                  const double* __restrict__ chsum,
                                                  const double* __restrict__ esum,
                                                  const double* __restrict__ zsq,
                                                  const double* __restrict__ enormsum,
                                                  float* __restrict__ out) {
    int t = threadIdx.x;
    double ent = 0.0;
    for (int i = t; i < KCODE; i += 256) {
        float em = (float)counts[i] / 32768.0f;
        ent += (double)(em * logf(em + 1e-10f));
    }
    double pd = chsum[t] * esum[t];

    __shared__ double r1[4], r2[4];
    for (int o2 = 32; o2; o2 >>= 1) {
        ent += __shfl_down(ent, o2, 64);
        pd  += __shfl_down(pd,  o2, 64);
    }
    if ((t & 63) == 0) { int w = t >> 6; r1[w] = ent; r2[w] = pd; }
    __syncthreads();
    if (t == 0) {
        double ENT = r1[0] + r1[1] + r1[2] + r1[3];
        double PD  = r2[0] + r2[1] + r2[2] + r2[3];
        float m = (float)(*lossSum / (double)ZELEMS);
        out[OUT_LOSS] = 0.25f * m + m;
        out[OUT_PERP] = expf((float)(-ENT));
        double md = *zsq / (double)NPTS + *enormsum / (double)KCODE
                    - (2.0 / ((double)NPTS * (double)KCODE)) * PD;
        out[OUT_MD] = (float)md;
    }
}

extern "C" void kernel_launch(void* const* d_in, const int* in_sizes, int n_in,
                              void* d_out, int out_size, void* d_ws, size_t ws_size,
                              hipStream_t stream) {
    const float* z  = (const float*)d_in[0];
    const float* cb = (const float*)d_in[1];
    float* out = (float*)d_out;
    char* ws = (char*)d_ws;

    int*    ws_idx   = (int*)(ws + WS_IDX);
    int*    counts   = (int*)(ws + WS_COUNTS);
    int*    rlist    = (int*)(ws + WS_RLIST);
    int*    rcount   = (int*)(ws + WS_RCOUNT);
    double* lossSum  = (double*)(ws + WS_LOSSSUM);
    double* zsq      = (double*)(ws + WS_ZSQ);
    double* enormsum = (double*)(ws + WS_ENSUM);
    double* chsum    = (double*)(ws + WS_CHSUM);
    double* esum     = (double*)(ws + WS_ESUM);
    float*  enorm    = (float*)(ws + WS_ENORM);
    float*  cbT      = (float*)(ws + WS_CBT);
    float*  colb     = (float*)(ws + WS_COLB);
    float*  colsec   = (float*)(ws + WS_COLS);
    int*    coli     = (int*)(ws + WS_COLI);

    hipLaunchKernelGGL(init_kernel, dim3(1), dim3(256), 0, stream, ws);
    hipLaunchKernelGGL(prep2_kernel, dim3(16), dim3(256), 0, stream, cb, enorm, cbT, esum, enormsum);
    hipLaunchKernelGGL(screen_kernel, dim3(128, 8), dim3(256), 0, stream,
                       z, cb, enorm, colb, colsec, coli);
    hipLaunchKernelGGL(merge_kernel, dim3(128), dim3(256), 0, stream,
                       colb, colsec, coli, ws_idx, rlist, rcount);
    hipLaunchKernelGGL(recheck_kernel, dim3(256), dim3(256), 0, stream,
                       z, cbT, enorm, ws_idx, rlist, rcount);
    hipLaunchKernelGGL(hist_kernel, dim3(128), dim3(256), 0, stream,
                       ws_idx, counts, out + OUT_IDX);
    hipLaunchKernelGGL(out_kernel, dim3(8192), dim3(256), 0, stream,
                       z, cb, ws_idx, out, lossSum, chsum, zsq);
    hipLaunchKernelGGL(fin_kernel, dim3(1), dim3(256), 0, stream,
                       counts, lossSum, chsum, esum, zsq, enormsum, out);
}

// Round 9
// 780.089 us; speedup vs baseline: 1.8695x; 1.8695x over previous
//
#include <hip/hip_runtime.h>
#include <hip/hip_bf16.h>

// Problem: VectorQuantizer. z: [32,256,32,32] f32 NCHW, codebook: [1024,256] f32.
// Outputs (concat f32): z_q_out [32,256,32,32], loss[1], perplexity[1], idx[32768] (as float), mean_distance[1].
// idx must replicate numpy-fp32 argmin of d = fl32(fl32(s_n + t_k) - 2*fl32(dot)).
// Screen via split-bf16 MFMA (3 products), exact-np recheck for near-ties.

#define NPTS   32768
#define KCODE  1024
#define DDIM   256
#define HWSZ   1024
#define ZSTRB  262144
#define ZELEMS 8388608

#define OUT_LOSS 8388608
#define OUT_PERP 8388609
#define OUT_IDX  8388610
#define OUT_MD   8421378

// ws byte offsets
#define WS_IDX     0        // int[32768]
#define WS_COUNTS  131072   // int[1024]
#define WS_RLIST   135168   // int[32768]
#define WS_RCOUNT  266240   // int
#define WS_LOSSSUM 266248   // double
#define WS_ZSQ     266256   // double
#define WS_ENSUM   266264   // double
#define WS_CHSUM   266272   // double[256]
#define WS_ESUM    268320   // double[256]
#define WS_ENORM   270368   // float[1024]
#define WS_CBT     274464   // float[256*1024]
#define WS_CBHI    1323040  // ushort[1024*256] bf16 hi
#define WS_CBLO    1847328  // ushort[1024*256] bf16 lo

// screen dot error (split-bf16+MFMA) ~1e-5; np flip window 6.2e-5; 2.4x headroom
#define MARGIN 2e-4f

typedef short  s16x8 __attribute__((ext_vector_type(8)));
typedef unsigned short u16x8 __attribute__((ext_vector_type(8)));
typedef float  f32x4 __attribute__((ext_vector_type(4)));

__device__ __forceinline__ unsigned short bf16_rne(float f) {
    unsigned int u = __float_as_uint(f);
    return (unsigned short)((u + 0x7FFFu + ((u >> 16) & 1u)) >> 16);
}

__global__ __launch_bounds__(256) void init_kernel(char* ws) {
    int t = threadIdx.x;
    int* counts = (int*)(ws + WS_COUNTS);
    for (int i = t; i < 1024; i += 256) counts[i] = 0;
    if (t == 0) *(int*)(ws + WS_RCOUNT) = 0;
    double* dbl = (double*)(ws + WS_LOSSSUM);
    for (int i = t; i < 515; i += 256) dbl[i] = 0.0;
}

// numpy pairwise fp32 sum of squares of a 256-row (exact tree; asm stops FMA contraction)
__device__ __forceinline__ float np_sumsq256(const float* p) {
    float tot[2];
    #pragma unroll
    for (int h = 0; h < 2; ++h) {
        const float* a = p + h * 128;
        float r[8];
        #pragma unroll
        for (int j = 0; j < 8; ++j) { float v = a[j]; float s = v * v; asm volatile("" : "+v"(s)); r[j] = s; }
        for (int i = 8; i < 128; i += 8) {
            #pragma unroll
            for (int j = 0; j < 8; ++j) { float v = a[i + j]; float s = v * v; asm volatile("" : "+v"(s)); r[j] += s; }
        }
        tot[h] = ((r[0] + r[1]) + (r[2] + r[3])) + ((r[4] + r[5]) + (r[6] + r[7]));
    }
    return tot[0] + tot[1];
}

// per 64 codes: np-fp32 enorm, cbT[d][k], cb hi/lo bf16, fp64 column sums + norm total
__global__ __launch_bounds__(256) void prep2_kernel(const float* __restrict__ cb,
                                                    float* __restrict__ enorm,
                                                    float* __restrict__ cbT,
                                                    unsigned short* __restrict__ cbhi,
                                                    unsigned short* __restrict__ cblo,
                                                    double* __restrict__ esum,
                                                    double* __restrict__ enormsum) {
    __shared__ float tile[64][257];
    int t = threadIdx.x;
    int k0 = blockIdx.x * 64;           // 16 blocks

    for (int i = 0; i < 16; ++i) {
        int f = t + 256 * i;
        int r = f >> 6;
        int c4 = (f & 63) << 2;
        float4 v = *(const float4*)(cb + (size_t)(k0 + r) * DDIM + c4);
        tile[r][c4] = v.x; tile[r][c4 + 1] = v.y; tile[r][c4 + 2] = v.z; tile[r][c4 + 3] = v.w;
    }
    __syncthreads();

    if (t < 64) {
        float s = np_sumsq256(&tile[t][0]);
        enorm[k0 + t] = s;
        double en = (double)s;
        for (int o = 32; o; o >>= 1) en += __shfl_down(en, o, 64);
        if (t == 0) atomicAdd(enormsum, en);
    }

    double cs = 0.0;
    for (int r = 0; r < 64; ++r) cs += (double)tile[r][t];
    atomicAdd(&esum[t], cs);

    // cbT transposed write for recheck
    {
        int kloc = t & 63, dq = t >> 6;
        for (int dd = 0; dd < 64; ++dd) {
            int d = dd * 4 + dq;
            cbT[(size_t)d * KCODE + k0 + kloc] = tile[kloc][d];
        }
    }

    // split-bf16 hi/lo rows (row-major [k][d])
    {
        int row = t >> 2, q = t & 3;
        #pragma unroll
        for (int j = 0; j < 8; ++j) {
            int d0 = q * 64 + j * 8;
            u16x8 H, L;
            #pragma unroll
            for (int e = 0; e < 8; ++e) {
                float f = tile[row][d0 + e];
                unsigned short h = bf16_rne(f);
                H[e] = h;
                L[e] = bf16_rne(f - __uint_as_float((unsigned int)h << 16));
            }
            *(u16x8*)(cbhi + (size_t)(k0 + row) * DDIM + d0) = H;
            *(u16x8*)(cblo + (size_t)(k0 + row) * DDIM + d0) = L;
        }
    }
}

// MFMA screen: 64 points/block (4 waves x 16-point tiles), all 1024 codes per wave.
// z staged in LDS as hi/lo bf16 (XOR-swizzled 16B slots); A-frags live in regs all kernel.
// dot = zh.eh + zh.el + zl.eh in 3 fp32 MFMA chains; criterion -> best/sec/idx;
// 16-lane shfl_xor merge (lowest-index ties; equal values flag for recheck).
__global__ __launch_bounds__(256, 2) void screen_kernel(const float* __restrict__ z,
                                                        const unsigned short* __restrict__ cbhi,
                                                        const unsigned short* __restrict__ cblo,
                                                        const float* __restrict__ enorm,
                                                        int* __restrict__ ws_idx,
                                                        int* __restrict__ rlist,
                                                        int* __restrict__ rcount) {
    __shared__ unsigned short zhi_lds[64 * DDIM];   // 32 KB
    __shared__ unsigned short zlo_lds[64 * DDIM];   // 32 KB
    int tid = threadIdx.x;
    int n0 = blockIdx.x * 64;
    int b = n0 >> 10, hw0 = n0 & 1023;
    const float* zb = z + (size_t)b * ZSTRB;
    char* zh = (char*)zhi_lds;
    char* zl = (char*)zlo_lds;

    // stage z tile: coalesced float4 reads (4 points x 1 channel), split + swizzled u16 stores.
    // element (p,d) at byte p*512 + ((d*2) ^ ((p&7)<<4))  [XOR touches bits 4-6 only]
    for (int i = 0; i < 16; ++i) {
        int f = tid + 256 * i;
        int d = f >> 4;
        int p4 = (f & 15) << 2;
        float4 v = *(const float4*)(zb + d * HWSZ + hw0 + p4);
        float vv[4] = {v.x, v.y, v.z, v.w};
        #pragma unroll
        for (int j = 0; j < 4; ++j) {
            int p = p4 + j;
            int off = (p << 9) + (((d << 1)) ^ ((p & 7) << 4));
            unsigned short hi = bf16_rne(vv[j]);
            *(unsigned short*)(zh + off) = hi;
            *(unsigned short*)(zl + off) = bf16_rne(vv[j] - __uint_as_float((unsigned int)hi << 16));
        }
    }
    __syncthreads();

    int lane = tid & 63;
    int w = tid >> 6;
    int col = lane & 15;        // A-row (point) and B-col (code) slot
    int kq = lane >> 4;         // K-quarter
    int rowl = w * 16 + col;    // local point index for A
    int swz = (rowl & 7) << 4;

    // A-fragments (8 K-chunks x hi/lo), held in registers for the whole kernel
    s16x8 ah[8], al[8];
    #pragma unroll
    for (int kc = 0; kc < 8; ++kc) {
        int off = (rowl << 9) + ((kc * 64 + kq * 16) ^ swz);
        ah[kc] = *(const s16x8*)(zh + off);
        al[kc] = *(const s16x8*)(zl + off);
    }

    float best[4] = {3.4e38f, 3.4e38f, 3.4e38f, 3.4e38f};
    float sec[4]  = {3.4e38f, 3.4e38f, 3.4e38f, 3.4e38f};
    int bidx[4] = {0, 0, 0, 0};

    const char* bhbase = (const char*)cbhi + col * 512 + kq * 16;
    const char* blbase = (const char*)cblo + col * 512 + kq * 16;

    #pragma unroll 1
    for (int chunk = 0; chunk < 64; ++chunk) {
        const char* bh = bhbase + chunk * 8192;
        const char* bl = blbase + chunk * 8192;
        f32x4 hh = {0.f, 0.f, 0.f, 0.f};
        f32x4 hl = {0.f, 0.f, 0.f, 0.f};
        f32x4 lh = {0.f, 0.f, 0.f, 0.f};
        #pragma unroll
        for (int kc = 0; kc < 8; ++kc) {
            s16x8 vbh = *(const s16x8*)(bh + kc * 64);
            s16x8 vbl = *(const s16x8*)(bl + kc * 64);
            hh = __builtin_amdgcn_mfma_f32_16x16x32_bf16(ah[kc], vbh, hh, 0, 0, 0);
            lh = __builtin_amdgcn_mfma_f32_16x16x32_bf16(al[kc], vbh, lh, 0, 0, 0);
            hl = __builtin_amdgcn_mfma_f32_16x16x32_bf16(ah[kc], vbl, hl, 0, 0, 0);
        }
        int k = chunk * 16 + col;
        float ek = enorm[k];
        #pragma unroll
        for (int r = 0; r < 4; ++r) {
            float dot = hh[r] + hl[r] + lh[r];
            float c = fmaf(-2.f, dot, ek);
            if (c < best[r]) { sec[r] = best[r]; best[r] = c; bidx[r] = k; }
            else if (c < sec[r]) sec[r] = c;
        }
    }

    // merge across the 16 code-columns (butterfly); ties -> lower idx; equal values leave sec==best -> flagged
    #pragma unroll
    for (int m = 1; m < 16; m <<= 1) {
        #pragma unroll
        for (int r = 0; r < 4; ++r) {
            float ob = __shfl_xor(best[r], m, 64);
            float os = __shfl_xor(sec[r], m, 64);
            int   oi = __shfl_xor(bidx[r], m, 64);
            if (ob < best[r] || (ob == best[r] && oi < bidx[r])) {
                sec[r] = fminf(best[r], os);
                best[r] = ob; bidx[r] = oi;
            } else {
                sec[r] = fminf(sec[r], ob);
            }
        }
    }

    if (col == 0) {
        #pragma unroll
        for (int r = 0; r < 4; ++r) {
            int n = n0 + w * 16 + kq * 4 + r;   // C row = kq*4 + r
            ws_idx[n] = bidx[r];
            if (sec[r] - best[r] < MARGIN) {
                int slot = atomicAdd(rcount, 1);
                if (slot < NPTS) rlist[slot] = n;
            }
        }
    }
}

// Recheck flagged points replicating numpy fp32 semantics (unchanged; passed).
__global__ __launch_bounds__(256) void recheck_kernel(const float* __restrict__ z,
                                                      const float* __restrict__ cbT,
                                                      const float* __restrict__ enorm,
                                                      int* __restrict__ ws_idx,
                                                      const int* __restrict__ rlist,
                                                      const int* __restrict__ rcount) {
    __shared__ float zs[DDIM];
    __shared__ float s_sh;
    __shared__ float bv[256];
    __shared__ int   bi[256];
    int t = threadIdx.x;
    int cnt = *rcount; if (cnt > NPTS) cnt = NPTS;
    for (int it = blockIdx.x; it < cnt; it += gridDim.x) {
        int n = rlist[it];
        int b = n >> 10, hw = n & 1023;
        zs[t] = z[(size_t)b * ZSTRB + (size_t)t * HWSZ + hw];
        __syncthreads();
        if (t == 0) s_sh = np_sumsq256(zs);
        __syncthreads();
        float s_n = s_sh;
        float best = 3.4e38f; int bidx = 0;
        #pragma unroll
        for (int j = 0; j < 4; ++j) {
            int k = t + 256 * j;
            double dot = 0.0;
            for (int d = 0; d < DDIM; ++d)
                dot = fma((double)cbT[d * KCODE + k], (double)zs[d], dot);
            float E = (float)dot;
            float w = 2.0f * E;
            float u = s_n + enorm[k];
            float dd = u - w;
            if (dd < best) { best = dd; bidx = k; }
        }
        bv[t] = best; bi[t] = bidx;
        __syncthreads();
        for (int s2 = 128; s2; s2 >>= 1) {
            if (t < s2) {
                if (bv[t + s2] < bv[t] || (bv[t + s2] == bv[t] && bi[t + s2] < bi[t])) {
                    bv[t] = bv[t + s2]; bi[t] = bi[t + s2];
                }
            }
            __syncthreads();
        }
        if (t == 0) ws_idx[n] = bi[0];
        __syncthreads();
    }
}

__global__ __launch_bounds__(256) void hist_kernel(const int* __restrict__ ws_idx,
                                                   int* __restrict__ counts,
                                                   float* __restrict__ out_idx) {
    __shared__ int h[KCODE];
    int t = threadIdx.x;
    for (int i = t; i < KCODE; i += 256) h[i] = 0;
    __syncthreads();
    int n = blockIdx.x * 256 + t;
    int idx = ws_idx[n];
    out_idx[n] = (float)idx;
    atomicAdd(&h[idx], 1);
    __syncthreads();
    for (int i = t; i < KCODE; i += 256) { int c = h[i]; if (c) atomicAdd(&counts[i], c); }
}

__global__ __launch_bounds__(256) void out_kernel(const float* __restrict__ z,
                                                  const float* __restrict__ cb,
                                                  const int* __restrict__ ws_idx,
                                                  float* __restrict__ out,
                                                  double* __restrict__ lossSum,
                                                  double* __restrict__ chsum,
                                                  double* __restrict__ zsq) {
    int t = threadIdx.x;
    size_t base = (size_t)blockIdx.x * 1024;
    int c = blockIdx.x & 255;
    int b = blockIdx.x >> 8;
    int hw = t * 4;
    const float4 zv = *(const float4*)(z + base + hw);
    int4 iv = *(const int4*)(ws_idx + b * HWSZ + hw);
    float q0 = cb[(size_t)iv.x * DDIM + c];
    float q1 = cb[(size_t)iv.y * DDIM + c];
    float q2 = cb[(size_t)iv.z * DDIM + c];
    float q3 = cb[(size_t)iv.w * DDIM + c];
    float t0 = q0 - zv.x, t1 = q1 - zv.y, t2 = q2 - zv.z, t3 = q3 - zv.w;
    float4 o; o.x = zv.x + t0; o.y = zv.y + t1; o.z = zv.z + t2; o.w = zv.w + t3;
    *(float4*)(out + base + hw) = o;

    double ls  = (double)t0 * t0 + (double)t1 * t1 + (double)t2 * t2 + (double)t3 * t3;
    double zs  = (double)zv.x + (double)zv.y + (double)zv.z + (double)zv.w;
    double zq2 = (double)zv.x * zv.x + (double)zv.y * zv.y + (double)zv.z * zv.z + (double)zv.w * zv.w;

    __shared__ double r1[4], r2[4], r3[4];
    for (int o2 = 32; o2; o2 >>= 1) {
        ls  += __shfl_down(ls,  o2, 64);
        zs  += __shfl_down(zs,  o2, 64);
        zq2 += __shfl_down(zq2, o2, 64);
    }
    if ((t & 63) == 0) { int w = t >> 6; r1[w] = ls; r2[w] = zs; r3[w] = zq2; }
    __syncthreads();
    if (t == 0) {
        atomicAdd(lossSum, r1[0] + r1[1] + r1[2] + r1[3]);
        atomicAdd(&chsum[c], r2[0] + r2[1] + r2[2] + r2[3]);
        atomicAdd(zsq, r3[0] + r3[1] + r3[2] + r3[3]);
    }
}

__global__ __launch_bounds__(256) void fin_kernel(const int* __restrict__ counts,
                                                  const double* __restrict__ lossSum,
                                                  const double* __restrict__ chsum,
                                                  const double* __restrict__ esum,
                                                  const double* __restrict__ zsq,
                                                  const double* __restrict__ enormsum,
                                                  float* __restrict__ out) {
    int t = threadIdx.x;
    double ent = 0.0;
    for (int i = t; i < KCODE; i += 256) {
        float em = (float)counts[i] / 32768.0f;
        ent += (double)(em * logf(em + 1e-10f));
    }
    double pd = chsum[t] * esum[t];

    __shared__ double r1[4], r2[4];
    for (int o2 = 32; o2; o2 >>= 1) {
        ent += __shfl_down(ent, o2, 64);
        pd  += __shfl_down(pd,  o2, 64);
    }
    if ((t & 63) == 0) { int w = t >> 6; r1[w] = ent; r2[w] = pd; }
    __syncthreads();
    if (t == 0) {
        double ENT = r1[0] + r1[1] + r1[2] + r1[3];
        double PD  = r2[0] + r2[1] + r2[2] + r2[3];
        float m = (float)(*lossSum / (double)ZELEMS);
        out[OUT_LOSS] = 0.25f * m + m;
        out[OUT_PERP] = expf((float)(-ENT));
        double md = *zsq / (double)NPTS + *enormsum / (double)KCODE
                    - (2.0 / ((double)NPTS * (double)KCODE)) * PD;
        out[OUT_MD] = (float)md;
    }
}

extern "C" void kernel_launch(void* const* d_in, const int* in_sizes, int n_in,
                              void* d_out, int out_size, void* d_ws, size_t ws_size,
                              hipStream_t stream) {
    const float* z  = (const float*)d_in[0];
    const float* cb = (const float*)d_in[1];
    float* out = (float*)d_out;
    char* ws = (char*)d_ws;

    int*    ws_idx   = (int*)(ws + WS_IDX);
    int*    counts   = (int*)(ws + WS_COUNTS);
    int*    rlist    = (int*)(ws + WS_RLIST);
    int*    rcount   = (int*)(ws + WS_RCOUNT);
    double* lossSum  = (double*)(ws + WS_LOSSSUM);
    double* zsq      = (double*)(ws + WS_ZSQ);
    double* enormsum = (double*)(ws + WS_ENSUM);
    double* chsum    = (double*)(ws + WS_CHSUM);
    double* esum     = (double*)(ws + WS_ESUM);
    float*  enorm    = (float*)(ws + WS_ENORM);
    float*  cbT      = (float*)(ws + WS_CBT);
    unsigned short* cbhi = (unsigned short*)(ws + WS_CBHI);
    unsigned short* cblo = (unsigned short*)(ws + WS_CBLO);

    hipLaunchKernelGGL(init_kernel, dim3(1), dim3(256), 0, stream, ws);
    hipLaunchKernelGGL(prep2_kernel, dim3(16), dim3(256), 0, stream,
                       cb, enorm, cbT, cbhi, cblo, esum, enormsum);
    hipLaunchKernelGGL(screen_kernel, dim3(512), dim3(256), 0, stream,
                       z, cbhi, cblo, enorm, ws_idx, rlist, rcount);
    hipLaunchKernelGGL(recheck_kernel, dim3(256), dim3(256), 0, stream,
                       z, cbT, enorm, ws_idx, rlist, rcount);
    hipLaunchKernelGGL(hist_kernel, dim3(128), dim3(256), 0, stream,
                       ws_idx, counts, out + OUT_IDX);
    hipLaunchKernelGGL(out_kernel, dim3(8192), dim3(256), 0, stream,
                       z, cb, ws_idx, out, lossSum, chsum, zsq);
    hipLaunchKernelGGL(fin_kernel, dim3(1), dim3(256), 0, stream,
                       counts, lossSum, chsum, esum, zsq, enormsum, out);
}